// Round 14
// baseline (2514.716 us; speedup 1.0000x reference)
//
#include <hip/hip_runtime.h>

#define N1 32768
#define NP1 512
#define NS1 32
#define N2 512
#define NP2 256
#define NS2 64
#define POISON 0xAAAAAAAAu

// ---- exact-rounding helpers: replicate reference op-by-op (NO fma/contract) ----
__device__ __forceinline__ float fadd(float a, float b){ return __fadd_rn(a,b); }
__device__ __forceinline__ float fmul(float a, float b){ return __fmul_rn(a,b); }
__device__ __forceinline__ float fsub(float a, float b){ return __fsub_rn(a,b); }

__device__ __forceinline__ float dist3(float px,float py,float pz,float cx,float cy,float cz){
    float dx = fsub(px,cx), dy = fsub(py,cy), dz = fsub(pz,cz);
    return fadd(fadd(fmul(dx,dx), fmul(dy,dy)), fmul(dz,dz));
}
__device__ __forceinline__ float sumsq3(float x,float y,float z){
    return fadd(fadd(fmul(x,x), fmul(y,y)), fmul(z,z));
}
__device__ __forceinline__ float dot3(float ax,float ay,float az,float bx,float by,float bz){
    return fadd(fadd(fmul(ax,bx), fmul(ay,by)), fmul(az,bz));
}
__device__ __forceinline__ unsigned long long shflmax64(unsigned long long k, int off){
    unsigned long long o = __shfl_xor(k, off, 64);
    return o > k ? o : k;
}

// ---- agent-scope atomic publish / poison-poll consume ----
__device__ __forceinline__ void astore_f(float* p, float v){
    __hip_atomic_store((unsigned*)p, __float_as_uint(v), __ATOMIC_RELAXED, __HIP_MEMORY_SCOPE_AGENT);
}
__device__ __forceinline__ void astore_i(int* p, int v){
    __hip_atomic_store((unsigned*)p, (unsigned)v, __ATOMIC_RELAXED, __HIP_MEMORY_SCOPE_AGENT);
}
template<int SLP>
__device__ __forceinline__ float poll_f(const float* p){
    unsigned v;
    for(;;){
        v = __hip_atomic_load((const unsigned*)p, __ATOMIC_RELAXED, __HIP_MEMORY_SCOPE_AGENT);
        if (v != POISON) break;
        __builtin_amdgcn_s_sleep(SLP);
    }
    return __uint_as_float(v);
}
template<int SLP>
__device__ __forceinline__ int poll_i(const int* p){
    unsigned v;
    for(;;){
        v = __hip_atomic_load((const unsigned*)p, __ATOMIC_RELAXED, __HIP_MEMORY_SCOPE_AGENT);
        if (v != POISON) break;
        __builtin_amdgcn_s_sleep(SLP);
    }
    return (int)v;
}

// ==================  PERSISTENT MEGA KERNEL: 984 blocks, ALL co-resident  ==================
// Capacity: 4 blocks/CU x 256 CUs = 1024 (LDS 33792 B -> 4/CU; VGPR 68 -> 16
// waves/CU — both measured in R13 with identical stage bodies). 984 <= 1024,
// so every block is resident from t=0: consumers start the instant their
// input is published (no R13 dispatch ramp, which cost ~150-200us).
// Stage layout (stage-major; persistent loops use interleaved s so earliest-
// published centroids are processed first):
//   [0,128)    fps1   m=l&15, b=l>>4 (R6-exact, proven)
//   [128,192)  ball1  8 blk/batch x 4 waves, each wave loops 16 centroids
//   [192,200)  fps2   1 blk/batch
//   [200,456)  mlp1   32 blk/batch, each loops 16 centroids
//   [456,472)  ball2  2 blk/batch x 4 waves, each wave loops 32 centroids
//   [472,984)  mlp2   64 blk/batch, each loops 4 centroids
// Deadlock-free: all producers resident from t=0; polls target only earlier
// stages; ws re-poisoned per launch (replay-safe).
#define FPS1_M  16
#define L_B1   128
#define L_F2   192
#define L_M1   200
#define L_B2   456
#define L_M2   472
#define L_TOT  984

__global__ __launch_bounds__(256) void mega_kernel(const float* __restrict__ xyz,
    float* __restrict__ new_xyz1, unsigned long long* __restrict__ bests,
    int* __restrict__ idx1, float r2a,
    float* __restrict__ new_xyz2, float* __restrict__ out0,
    const float* __restrict__ M1W1, const float* __restrict__ M1B1,
    const float* __restrict__ M1W2, const float* __restrict__ M1B2,
    const float* __restrict__ M1W3, const float* __restrict__ M1B3,
    float* __restrict__ l1_points,
    int* __restrict__ idx2, float r2b,
    const float* __restrict__ M2W1, const float* __restrict__ M2B1,
    const float* __restrict__ M2W2, const float* __restrict__ M2B2,
    const float* __restrict__ M2W3, const float* __restrict__ M2B3,
    float* __restrict__ out1)
{
    const int l = blockIdx.x;
    const int t = threadIdx.x;
    const int lane = t & 63;
    const int wid  = t >> 6;

    __shared__ unsigned long long wb[4];
    __shared__ float cw[4];
    __shared__ __align__(16) float ldsA[32*132];   // 16896 B (multi-purpose)
    __shared__ __align__(16) float ldsB[32*128];   // 16384 B
    __shared__ int sidx_sh[64];

    if (l < L_B1) {
        // ---------------- fps1 (R6-exact body) ----------------
        const int m = l & 15;
        const int b = l >> 4;
        const float* xb = xyz + (size_t)b * 6 * N1;
        const int base = m * (N1 / FPS1_M);
        float px[8], py[8], pz[8], dd[8];
#pragma unroll
        for (int j = 0; j < 8; ++j) {
            int n = base + t + j * 256;
            px[j] = xb[n];
            py[j] = xb[N1 + n];
            pz[j] = xb[2*N1 + n];
            dd[j] = 1e10f;
        }
        float cx = xb[0], cy = xb[N1], cz = xb[2*N1];

        for (int s = 0; s < NP1; ++s) {
            if (m == 0 && t == 0) {
                float* o = new_xyz1 + ((size_t)b*NP1 + s)*3;
                astore_f(o+0, cx); astore_f(o+1, cy); astore_f(o+2, cz);
            }
            if (s == NP1 - 1) break;

            float bv = -1.0f; int bi = base + t;
#pragma unroll
            for (int j = 0; j < 8; ++j) {
                float d  = dist3(px[j],py[j],pz[j],cx,cy,cz);
                float nd = fminf(dd[j], d);
                dd[j] = nd;
                if (nd > bv) { bv = nd; bi = base + t + j*256; }
            }
            unsigned long long pk = ((unsigned long long)__float_as_uint(bv) << 15)
                                  | (unsigned long long)(32767 - bi);
            pk = shflmax64(pk, 1);  pk = shflmax64(pk, 2);  pk = shflmax64(pk, 4);
            pk = shflmax64(pk, 8);  pk = shflmax64(pk, 16); pk = shflmax64(pk, 32);
            if (lane == 0) wb[wid] = pk;
            __syncthreads();

            if (wid == 0) {
                unsigned long long k4 = (lane < 4) ? wb[lane] : 0ull;
                k4 = shflmax64(k4, 1); k4 = shflmax64(k4, 2);
                unsigned long long* slotPar = bests + ((size_t)b*2 + (s & 1))*FPS1_M;
                if (lane == 0)
                    __hip_atomic_store(slotPar + m, (k4 << 10) | (unsigned long long)s,
                                       __ATOMIC_RELAXED, __HIP_MEMORY_SCOPE_AGENT);
                unsigned long long myv = 0; bool done = (lane >= FPS1_M);
                float ccx = 0.f, ccy = 0.f, ccz = 0.f;
                while (__ballot(done) != 0xFFFFFFFFFFFFFFFFull) {
                    if (!done) {
                        unsigned long long v = __hip_atomic_load(slotPar + lane,
                                                 __ATOMIC_RELAXED, __HIP_MEMORY_SCOPE_AGENT);
                        if ((unsigned)(v & 1023ull) == (unsigned)s) {
                            done = true; myv = v;
                            int idx = 32767 - (int)((v >> 10) & 0x7fffull);
                            ccx = xb[idx]; ccy = xb[N1 + idx]; ccz = xb[2*N1 + idx];
                        }
                    }
                }
                unsigned long long w = myv;
                w = shflmax64(w, 1); w = shflmax64(w, 2); w = shflmax64(w, 4); w = shflmax64(w, 8);
                int wl = (int)__ffsll(__ballot(myv == w)) - 1;
                float ncx = __shfl(ccx, wl, 64);
                float ncy = __shfl(ccy, wl, 64);
                float ncz = __shfl(ccz, wl, 64);
                if (lane == 0) { cw[0] = ncx; cw[1] = ncy; cw[2] = ncz; }
            }
            __syncthreads();
            cx = cw[0]; cy = cw[1]; cz = cw[2];
        }
        return;
    }

    if (l < L_F2) {
        // ---------------- ball1: persistent, 1 wave/centroid, 16 centroids/wave ----------------
        const int i = l - L_B1;
        const int b = i >> 3;                    // 8 blocks/batch
        const int wu = (i & 7)*4 + wid;          // wave unit 0..31 in batch
        const float* xb = xyz + (size_t)b*6*N1;
        for (int k = 0; k < 16; ++k) {
            const int s = wu + 32*k;             // interleaved: earliest s first
            const float* cp = new_xyz1 + ((size_t)b*NP1 + s)*3;
            float cx = poll_f<16>(cp+0), cy = poll_f<16>(cp+1), cz = poll_f<16>(cp+2);

            float snew = sumsq3(cx,cy,cz);
            int* out = idx1 + ((size_t)b*NP1 + s)*NS1;
            int cnt = 0, first = 0;
            for (int ch = 0; ch < N1/64; ++ch) {
                int n = ch*64 + lane;
                float x = xb[n], y = xb[N1+n], z = xb[2*N1+n];
                float sx  = sumsq3(x,y,z);
                float dt  = dot3(cx,cy,cz,x,y,z);
                float sqr = fsub(fadd(snew, sx), fmul(2.0f, dt));
                bool inb = !(sqr > r2a);
                unsigned long long mask = __ballot(inb);
                if (mask) {
                    if (cnt == 0) first = ch*64 + (int)(__ffsll((unsigned long long)mask) - 1);
                    if (inb) {
                        int pos = cnt + (int)__popcll(mask & ((1ull << lane) - 1ull));
                        if (pos < NS1) astore_i(out + pos, n);
                    }
                    cnt += (int)__popcll(mask);
                    if (cnt >= NS1) break;
                }
            }
            int c = cnt < NS1 ? cnt : NS1;
            if (lane < NS1 && lane >= c) astore_i(out + lane, first);
        }
        return;
    }

    if (l < L_M1) {
        // ---------------- fps2: poll-stage new_xyz1, 1-wave FPS ----------------
        const int b = l - L_F2;
        float* c3 = ldsA;
        const float* src = new_xyz1 + (size_t)b*N2*3;
        for (int e = t; e < N2*3; e += 256) c3[e] = poll_f<2>(src + e);
        __syncthreads();
        if (t >= 64) return;

        float px[8], py[8], pz[8], dd[8];
#pragma unroll
        for (int j = 0; j < 8; ++j) {
            int n = t + j*64;
            px[j] = c3[n*3]; py[j] = c3[n*3+1]; pz[j] = c3[n*3+2];
            dd[j] = 1e10f;
        }
        int cur = 0;
        for (int s = 0; s < NP2; ++s) {
            float cx = c3[cur*3], cy = c3[cur*3+1], cz = c3[cur*3+2];
            if (t == 0) {
                float* o = new_xyz2 + ((size_t)b*NP2 + s)*3;
                astore_f(o+0, cx); astore_f(o+1, cy); astore_f(o+2, cz);
                out0[b*3*NP2 + s]         = cx;
                out0[b*3*NP2 + NP2 + s]   = cy;
                out0[b*3*NP2 + 2*NP2 + s] = cz;
            }
            float bv = -1.0f; int bi = 0;
#pragma unroll
            for (int j = 0; j < 8; ++j) {
                float d  = dist3(px[j],py[j],pz[j],cx,cy,cz);
                float nd = fminf(dd[j], d);
                dd[j] = nd;
                int n = t + j*64;
                if (nd > bv) { bv = nd; bi = n; }
            }
            unsigned long long pk = ((unsigned long long)__float_as_uint(bv) << 9)
                                  | (unsigned long long)(511 - bi);
            pk = shflmax64(pk, 1);  pk = shflmax64(pk, 2);  pk = shflmax64(pk, 4);
            pk = shflmax64(pk, 8);  pk = shflmax64(pk, 16); pk = shflmax64(pk, 32);
            cur = 511 - (int)(pk & 511ull);
        }
        return;
    }

    if (l < L_B2) {
        // ---------------- mlp1: persistent, 1 centroid/block-iter, 16 iters ----------------
        const int i = l - L_M1;
        const int b = i >> 5;                    // 32 blocks/batch
        const int j0 = i & 31;
        const float* xb = xyz + (size_t)b*6*N1;
        float (*inb6)[6]   = (float(*)[6])ldsA;
        float (*h1m)[64]   = (float(*)[64])(ldsA + 192);
        float (*h2m)[64]   = (float(*)[64])ldsB;
        float (*redm)[128] = (float(*)[128])(ldsB + 2048);

        for (int it = 0; it < 16; ++it) {
            const int s = j0 + 32*it;            // interleaved: earliest s first
            const float* cp = new_xyz1 + ((size_t)b*NP1 + s)*3;
            float c0 = poll_f<16>(cp+0), c1 = poll_f<16>(cp+1), c2 = poll_f<16>(cp+2);
            if (t < NS1) sidx_sh[t] = poll_i<16>(idx1 + ((size_t)b*NP1+s)*NS1 + t);
            __syncthreads();
            if (t < NS1*6) {
                int k = t / 6, c = t % 6;
                int n = sidx_sh[k];
                float v = xb[(size_t)c*N1 + n];
                if (c == 0) v -= c0; else if (c == 1) v -= c1; else if (c == 2) v -= c2;
                inb6[k][c] = v;
            }
            __syncthreads();
            {   // L1
                int o = t & 63, kg = t >> 6;
                float w[6];
#pragma unroll
                for (int c = 0; c < 6; ++c) w[c] = M1W1[o*6+c];
                float bias = M1B1[o];
#pragma unroll
                for (int kk = 0; kk < 8; ++kk) {
                    int k = kg*8 + kk;
                    float a = 0.f;
#pragma unroll
                    for (int c = 0; c < 6; ++c) a = fmaf(inb6[k][c], w[c], a);
                    h1m[k][o] = fmaxf(a + bias, 0.f);
                }
            }
            __syncthreads();
            {   // L2: 64 -> 64
                int o = t & 63, kg = t >> 6;
                float acc[8] = {};
                for (int ch = 0; ch < 8; ++ch) {
                    const float4 wa = *(const float4*)&M1W2[o*64 + ch*8];
                    const float4 wbv = *(const float4*)&M1W2[o*64 + ch*8 + 4];
#pragma unroll
                    for (int kk = 0; kk < 8; ++kk) {
                        int k = kg*8+kk;
                        const float4 a0 = *(const float4*)&h1m[k][ch*8];
                        const float4 a1 = *(const float4*)&h1m[k][ch*8+4];
                        acc[kk] = fmaf(a0.x, wa.x, acc[kk]);
                        acc[kk] = fmaf(a0.y, wa.y, acc[kk]);
                        acc[kk] = fmaf(a0.z, wa.z, acc[kk]);
                        acc[kk] = fmaf(a0.w, wa.w, acc[kk]);
                        acc[kk] = fmaf(a1.x, wbv.x, acc[kk]);
                        acc[kk] = fmaf(a1.y, wbv.y, acc[kk]);
                        acc[kk] = fmaf(a1.z, wbv.z, acc[kk]);
                        acc[kk] = fmaf(a1.w, wbv.w, acc[kk]);
                    }
                }
                float bias = M1B2[o];
#pragma unroll
                for (int kk = 0; kk < 8; ++kk) h2m[kg*8+kk][o] = fmaxf(acc[kk] + bias, 0.f);
            }
            __syncthreads();
            {   // L3: 64 -> 128 + max over samples
                int o = t & 127, kg = t >> 7;
                float acc[16] = {};
                for (int ch = 0; ch < 8; ++ch) {
                    const float4 wa = *(const float4*)&M1W3[o*64 + ch*8];
                    const float4 wbv = *(const float4*)&M1W3[o*64 + ch*8 + 4];
#pragma unroll
                    for (int kk = 0; kk < 16; ++kk) {
                        int k = kg*16+kk;
                        const float4 a0 = *(const float4*)&h2m[k][ch*8];
                        const float4 a1 = *(const float4*)&h2m[k][ch*8+4];
                        acc[kk] = fmaf(a0.x, wa.x, acc[kk]);
                        acc[kk] = fmaf(a0.y, wa.y, acc[kk]);
                        acc[kk] = fmaf(a0.z, wa.z, acc[kk]);
                        acc[kk] = fmaf(a0.w, wa.w, acc[kk]);
                        acc[kk] = fmaf(a1.x, wbv.x, acc[kk]);
                        acc[kk] = fmaf(a1.y, wbv.y, acc[kk]);
                        acc[kk] = fmaf(a1.z, wbv.z, acc[kk]);
                        acc[kk] = fmaf(a1.w, wbv.w, acc[kk]);
                    }
                }
                float bias = M1B3[o];
                float m = -1e30f;
#pragma unroll
                for (int kk = 0; kk < 16; ++kk) m = fmaxf(m, fmaxf(acc[kk] + bias, 0.f));
                redm[kg][o] = m;
            }
            __syncthreads();
            if (t < 128) {
                float m = fmaxf(redm[0][t], redm[1][t]);
                astore_f(l1_points + ((size_t)b*NP1+s)*128 + t, m);
            }
            __syncthreads();   // protect LDS reuse next iteration
        }
        return;
    }

    if (l < L_M2) {
        // ---------------- ball2: persistent, 1 wave/centroid, 32 centroids/wave ----------------
        const int i = l - L_B2;
        const int b = i >> 1;                    // 2 blocks/batch
        const int wu = (i & 1)*4 + wid;          // wave unit 0..7 in batch
        const float* pb = new_xyz1 + (size_t)b*N2*3;
        for (int k = 0; k < 32; ++k) {
            const int s = wu + 8*k;              // interleaved: earliest s first
            const float* cp = new_xyz2 + ((size_t)b*NP2 + s)*3;
            float cx = poll_f<4>(cp+0), cy = poll_f<4>(cp+1), cz = poll_f<4>(cp+2);
            float snew = sumsq3(cx,cy,cz);
            int* out = idx2 + ((size_t)b*NP2 + s)*NS2;
            int cnt = 0, first = 0;
            for (int ch = 0; ch < N2/64; ++ch) {
                int n = ch*64 + lane;
                float x = poll_f<4>(&pb[n*3]), y = poll_f<4>(&pb[n*3+1]), z = poll_f<4>(&pb[n*3+2]);
                float sx  = sumsq3(x,y,z);
                float dt  = dot3(cx,cy,cz,x,y,z);
                float sqr = fsub(fadd(snew, sx), fmul(2.0f, dt));
                bool inb = !(sqr > r2b);
                unsigned long long mask = __ballot(inb);
                if (mask) {
                    if (cnt == 0) first = ch*64 + (int)(__ffsll((unsigned long long)mask) - 1);
                    if (inb) {
                        int pos = cnt + (int)__popcll(mask & ((1ull << lane) - 1ull));
                        if (pos < NS2) astore_i(out + pos, n);
                    }
                    cnt += (int)__popcll(mask);
                    if (cnt >= NS2) break;
                }
            }
            int c = cnt < NS2 ? cnt : NS2;
            if (lane >= c) astore_i(out + lane, first);
        }
        return;
    }

    // ---------------- mlp2: persistent, 1 centroid/block-iter, 4 iters ----------------
    {
        const int i = l - L_M2;
        const int b = i >> 6;                    // 64 blocks/batch
        const int j0 = i & 63;
        float (*inb2)[132] = (float(*)[132])ldsA;   // aliased with h2_
        float (*h1_)[128]  = (float(*)[128])ldsB;
        float (*h2_)[128]  = (float(*)[128])ldsA;

        for (int it = 0; it < 4; ++it) {
            const int s = j0 + 64*it;            // interleaved: earliest s first
            const float* cp = new_xyz2 + ((size_t)b*NP2+s)*3;
            float c0 = poll_f<4>(cp+0), c1 = poll_f<4>(cp+1), c2 = poll_f<4>(cp+2);
            if (t < NS2) sidx_sh[t] = poll_i<4>(idx2 + ((size_t)b*NP2+s)*NS2 + t);

            const int o1 = t & 63, o2 = o1 + 64, g = t >> 6;
            float vmax0 = -1e30f, vmax1 = -1e30f;

            for (int half = 0; half < 2; ++half) {
                __syncthreads();
                for (int e = t; e < 32*128; e += 256) {
                    int kk = e >> 7, c = e & 127;
                    int n = sidx_sh[half*32 + kk];
                    inb2[kk][c] = poll_f<4>(l1_points + ((size_t)b*N2 + n)*128 + c);
                }
                for (int e = t; e < 32*3; e += 256) {
                    int kk = e / 3, c = e % 3;
                    int n = sidx_sh[half*32 + kk];
                    inb2[kk][128 + c] = poll_f<4>(new_xyz1 + ((size_t)b*N2 + n)*3 + c)
                                      - (c==0 ? c0 : (c==1 ? c1 : c2));
                }
                __syncthreads();
                {   // L1: 131 -> 128, 2 outputs x 8 samples per thread
                    float accA[8] = {}, accB[8] = {};
                    for (int ch = 0; ch < 16; ++ch) {
                        float wa[8], wbv[8];
#pragma unroll
                        for (int j = 0; j < 8; ++j) {
                            wa[j]  = M2W1[o1*131 + 3 + ch*8 + j];
                            wbv[j] = M2W1[o2*131 + 3 + ch*8 + j];
                        }
#pragma unroll
                        for (int kk = 0; kk < 8; ++kk) {
                            int k = g*8 + kk;
                            const float4 a0 = *(const float4*)&inb2[k][ch*8];
                            const float4 a1 = *(const float4*)&inb2[k][ch*8+4];
                            accA[kk] = fmaf(a0.x, wa[0], accA[kk]);
                            accA[kk] = fmaf(a0.y, wa[1], accA[kk]);
                            accA[kk] = fmaf(a0.z, wa[2], accA[kk]);
                            accA[kk] = fmaf(a0.w, wa[3], accA[kk]);
                            accA[kk] = fmaf(a1.x, wa[4], accA[kk]);
                            accA[kk] = fmaf(a1.y, wa[5], accA[kk]);
                            accA[kk] = fmaf(a1.z, wa[6], accA[kk]);
                            accA[kk] = fmaf(a1.w, wa[7], accA[kk]);
                            accB[kk] = fmaf(a0.x, wbv[0], accB[kk]);
                            accB[kk] = fmaf(a0.y, wbv[1], accB[kk]);
                            accB[kk] = fmaf(a0.z, wbv[2], accB[kk]);
                            accB[kk] = fmaf(a0.w, wbv[3], accB[kk]);
                            accB[kk] = fmaf(a1.x, wbv[4], accB[kk]);
                            accB[kk] = fmaf(a1.y, wbv[5], accB[kk]);
                            accB[kk] = fmaf(a1.z, wbv[6], accB[kk]);
                            accB[kk] = fmaf(a1.w, wbv[7], accB[kk]);
                        }
                    }
                    float ta0=M2W1[o1*131+0], ta1=M2W1[o1*131+1], ta2=M2W1[o1*131+2];
                    float tb0=M2W1[o2*131+0], tb1=M2W1[o2*131+1], tb2=M2W1[o2*131+2];
                    float biasA = M2B1[o1], biasB = M2B1[o2];
#pragma unroll
                    for (int kk = 0; kk < 8; ++kk) {
                        int k = g*8 + kk;
                        float f0 = inb2[k][128], f1 = inb2[k][129], f2 = inb2[k][130];
                        float vA = accA[kk];
                        vA = fmaf(f0, ta0, vA); vA = fmaf(f1, ta1, vA); vA = fmaf(f2, ta2, vA);
                        float vB = accB[kk];
                        vB = fmaf(f0, tb0, vB); vB = fmaf(f1, tb1, vB); vB = fmaf(f2, tb2, vB);
                        h1_[k][o1] = fmaxf(vA + biasA, 0.f);
                        h1_[k][o2] = fmaxf(vB + biasB, 0.f);
                    }
                }
                __syncthreads();
                {   // L2: 128 -> 128 (writes h2_ = alias of inb2)
                    float accA[8] = {}, accB[8] = {};
                    for (int ch = 0; ch < 16; ++ch) {
                        const float4 wa0 = *(const float4*)&M2W2[o1*128 + ch*8];
                        const float4 wa1 = *(const float4*)&M2W2[o1*128 + ch*8 + 4];
                        const float4 wb0 = *(const float4*)&M2W2[o2*128 + ch*8];
                        const float4 wb1 = *(const float4*)&M2W2[o2*128 + ch*8 + 4];
#pragma unroll
                        for (int kk = 0; kk < 8; ++kk) {
                            int k = g*8 + kk;
                            const float4 a0 = *(const float4*)&h1_[k][ch*8];
                            const float4 a1 = *(const float4*)&h1_[k][ch*8+4];
                            accA[kk] = fmaf(a0.x, wa0.x, accA[kk]);
                            accA[kk] = fmaf(a0.y, wa0.y, accA[kk]);
                            accA[kk] = fmaf(a0.z, wa0.z, accA[kk]);
                            accA[kk] = fmaf(a0.w, wa0.w, accA[kk]);
                            accA[kk] = fmaf(a1.x, wa1.x, accA[kk]);
                            accA[kk] = fmaf(a1.y, wa1.y, accA[kk]);
                            accA[kk] = fmaf(a1.z, wa1.z, accA[kk]);
                            accA[kk] = fmaf(a1.w, wa1.w, accA[kk]);
                            accB[kk] = fmaf(a0.x, wb0.x, accB[kk]);
                            accB[kk] = fmaf(a0.y, wb0.y, accB[kk]);
                            accB[kk] = fmaf(a0.z, wb0.z, accB[kk]);
                            accB[kk] = fmaf(a0.w, wb0.w, accB[kk]);
                            accB[kk] = fmaf(a1.x, wb1.x, accB[kk]);
                            accB[kk] = fmaf(a1.y, wb1.y, accB[kk]);
                            accB[kk] = fmaf(a1.z, wb1.z, accB[kk]);
                            accB[kk] = fmaf(a1.w, wb1.w, accB[kk]);
                        }
                    }
                    float biasA = M2B2[o1], biasB = M2B2[o2];
#pragma unroll
                    for (int kk = 0; kk < 8; ++kk) {
                        int k = g*8 + kk;
                        h2_[k][o1] = fmaxf(accA[kk] + biasA, 0.f);
                        h2_[k][o2] = fmaxf(accB[kk] + biasB, 0.f);
                    }
                }
                __syncthreads();
                {   // L3: 128 -> 285, fold max over this half's 32 samples
                    {
                        float acc[32] = {};
                        for (int ch = 0; ch < 16; ++ch) {
                            const float4 w0 = *(const float4*)&M2W3[t*128 + ch*8];
                            const float4 w1 = *(const float4*)&M2W3[t*128 + ch*8 + 4];
#pragma unroll
                            for (int kk = 0; kk < 32; ++kk) {
                                const float4 a0 = *(const float4*)&h2_[kk][ch*8];
                                const float4 a1 = *(const float4*)&h2_[kk][ch*8+4];
                                acc[kk] = fmaf(a0.x, w0.x, acc[kk]);
                                acc[kk] = fmaf(a0.y, w0.y, acc[kk]);
                                acc[kk] = fmaf(a0.z, w0.z, acc[kk]);
                                acc[kk] = fmaf(a0.w, w0.w, acc[kk]);
                                acc[kk] = fmaf(a1.x, w1.x, acc[kk]);
                                acc[kk] = fmaf(a1.y, w1.y, acc[kk]);
                                acc[kk] = fmaf(a1.z, w1.z, acc[kk]);
                                acc[kk] = fmaf(a1.w, w1.w, acc[kk]);
                            }
                        }
                        float bias = M2B3[t];
                        float mm = vmax0;
#pragma unroll
                        for (int kk = 0; kk < 32; ++kk) mm = fmaxf(mm, fmaxf(acc[kk] + bias, 0.f));
                        vmax0 = mm;
                    }
                    if (t < 29) {
                        int o = t + 256;
                        float acc[32] = {};
                        for (int ch = 0; ch < 16; ++ch) {
                            const float4 w0 = *(const float4*)&M2W3[o*128 + ch*8];
                            const float4 w1 = *(const float4*)&M2W3[o*128 + ch*8 + 4];
#pragma unroll
                            for (int kk = 0; kk < 32; ++kk) {
                                const float4 a0 = *(const float4*)&h2_[kk][ch*8];
                                const float4 a1 = *(const float4*)&h2_[kk][ch*8+4];
                                acc[kk] = fmaf(a0.x, w0.x, acc[kk]);
                                acc[kk] = fmaf(a0.y, w0.y, acc[kk]);
                                acc[kk] = fmaf(a0.z, w0.z, acc[kk]);
                                acc[kk] = fmaf(a0.w, w0.w, acc[kk]);
                                acc[kk] = fmaf(a1.x, w1.x, acc[kk]);
                                acc[kk] = fmaf(a1.y, w1.y, acc[kk]);
                                acc[kk] = fmaf(a1.z, w1.z, acc[kk]);
                                acc[kk] = fmaf(a1.w, w1.w, acc[kk]);
                            }
                        }
                        float bias = M2B3[o];
                        float mm = vmax1;
#pragma unroll
                        for (int kk = 0; kk < 32; ++kk) mm = fmaxf(mm, fmaxf(acc[kk] + bias, 0.f));
                        vmax1 = mm;
                    }
                }
            }
            out1[((size_t)b*NP2+s)*285 + t] = vmax0;
            if (t < 29) out1[((size_t)b*NP2+s)*285 + t + 256] = vmax1;
            __syncthreads();   // protect LDS reuse next iteration
        }
    }
}

extern "C" void kernel_launch(void* const* d_in, const int* in_sizes, int n_in,
                              void* d_out, int out_size, void* d_ws, size_t ws_size,
                              hipStream_t stream)
{
    (void)in_sizes; (void)n_in; (void)out_size; (void)ws_size;
    const float* xyz  = (const float*)d_in[0];
    const float* s1w1 = (const float*)d_in[1];  const float* s1b1 = (const float*)d_in[2];
    const float* s1w2 = (const float*)d_in[3];  const float* s1b2 = (const float*)d_in[4];
    const float* s1w3 = (const float*)d_in[5];  const float* s1b3 = (const float*)d_in[6];
    const float* s2w1 = (const float*)d_in[7];  const float* s2b1 = (const float*)d_in[8];
    const float* s2w2 = (const float*)d_in[9];  const float* s2b2 = (const float*)d_in[10];
    const float* s2w3 = (const float*)d_in[11]; const float* s2b3 = (const float*)d_in[12];

    float* ws        = (float*)d_ws;
    float* new_xyz1  = ws;                  // 8*512*3   = 12288 f
    float* new_xyz2  = ws + 12288;          // 8*256*3   = 6144 f
    float* l1_points = ws + 18432;          // 8*512*128 = 524288 f
    int*   idx1      = (int*)(ws + 542720); // 8*512*32  = 131072 i
    int*   idx2      = idx1 + 131072;       // 8*256*64  = 131072 i
    unsigned long long* bests = (unsigned long long*)(ws + 804864); // 256 u64

    float* out0 = (float*)d_out;            // (8,3,256)
    float* out1 = out0 + 8*3*256;           // (8,256,285)

    const float r2a = (float)(0.025*0.025);
    const float r2b = (float)(0.05*0.05);

    mega_kernel<<<dim3(L_TOT), dim3(256), 0, stream>>>(xyz,
        new_xyz1, bests, idx1, r2a, new_xyz2, out0,
        s1w1,s1b1,s1w2,s1b2,s1w3,s1b3, l1_points,
        idx2, r2b,
        s2w1,s2b1,s2w2,s2b2,s2w3,s2b3, out1);
}

// Round 15
// 1693.467 us; speedup vs baseline: 1.4850x; 1.4850x over previous
//
#include <hip/hip_runtime.h>

#define N1 32768
#define NP1 512
#define NS1 32
#define N2 512
#define NP2 256
#define NS2 64
#define POISON 0xAAAAAAAAu

// ---- exact-rounding helpers: replicate reference op-by-op (NO fma/contract) ----
__device__ __forceinline__ float fadd(float a, float b){ return __fadd_rn(a,b); }
__device__ __forceinline__ float fmul(float a, float b){ return __fmul_rn(a,b); }
__device__ __forceinline__ float fsub(float a, float b){ return __fsub_rn(a,b); }

__device__ __forceinline__ float dist3(float px,float py,float pz,float cx,float cy,float cz){
    float dx = fsub(px,cx), dy = fsub(py,cy), dz = fsub(pz,cz);
    return fadd(fadd(fmul(dx,dx), fmul(dy,dy)), fmul(dz,dz));
}
__device__ __forceinline__ float sumsq3(float x,float y,float z){
    return fadd(fadd(fmul(x,x), fmul(y,y)), fmul(z,z));
}
__device__ __forceinline__ float dot3(float ax,float ay,float az,float bx,float by,float bz){
    return fadd(fadd(fmul(ax,bx), fmul(ay,by)), fmul(az,bz));
}
__device__ __forceinline__ unsigned long long shflmax64(unsigned long long k, int off){
    unsigned long long o = __shfl_xor(k, off, 64);
    return o > k ? o : k;
}

// ---- agent-scope atomic publish / poison-poll consume ----
__device__ __forceinline__ void astore_f(float* p, float v){
    __hip_atomic_store((unsigned*)p, __float_as_uint(v), __ATOMIC_RELAXED, __HIP_MEMORY_SCOPE_AGENT);
}
__device__ __forceinline__ void astore_i(int* p, int v){
    __hip_atomic_store((unsigned*)p, (unsigned)v, __ATOMIC_RELAXED, __HIP_MEMORY_SCOPE_AGENT);
}
template<int SLP>
__device__ __forceinline__ float poll_f(const float* p){
    unsigned v;
    for(;;){
        v = __hip_atomic_load((const unsigned*)p, __ATOMIC_RELAXED, __HIP_MEMORY_SCOPE_AGENT);
        if (v != POISON) break;
        __builtin_amdgcn_s_sleep(SLP);
    }
    return __uint_as_float(v);
}
template<int SLP>
__device__ __forceinline__ int poll_i(const int* p){
    unsigned v;
    for(;;){
        v = __hip_atomic_load((const unsigned*)p, __ATOMIC_RELAXED, __HIP_MEMORY_SCOPE_AGENT);
        if (v != POISON) break;
        __builtin_amdgcn_s_sleep(SLP);
    }
    return (int)v;
}

// ==================  MEGA KERNEL (R13 structure) + s-major stage order  ==================
// 1-D grid, stage-major dispatch (producers strictly before consumers).
// R14 lesson: do NOT make all stages co-resident (spin-poll contention doubled
// fps1's exchange latency). Keep R13's dispatch chain; ONLY change intra-stage
// block order to s-major (s outer, batch inner) so the 1024-block resident
// window tracks fps1's publication frontier across ALL batches:
//   [0,128)      fps1   m=l&15, b=l>>4 (R6-exact, proven)
//   [128,1152)   ball1  s-major: s4=i>>3, b=i&7, s=s4*4+wid
//   [1152,1160)  fps2   1 blk/batch
//   [1160,5256)  mlp1   s-major: s=i>>3, b=i&7
//   [5256,5768)  ball2  s-major: s4=i>>3, b=i&7, s=s4*4+wid
//   [5768,7816)  mlp2   s-major: s=i>>3, b=i&7
// All cross-stage traffic: relaxed agent atomics + poison-poll (0xAA
// unreachable for coords/feats/indices). Polls target only earlier stages ->
// grounded, no deadlock; ws re-poisoned per launch -> replay-safe.
#define FPS1_M  16
#define L_B1   128
#define L_F2   1152
#define L_M1   1160
#define L_B2   5256
#define L_M2   5768
#define L_TOT  7816

__global__ __launch_bounds__(256) void mega_kernel(const float* __restrict__ xyz,
    float* __restrict__ new_xyz1, unsigned long long* __restrict__ bests,
    int* __restrict__ idx1, float r2a,
    float* __restrict__ new_xyz2, float* __restrict__ out0,
    const float* __restrict__ M1W1, const float* __restrict__ M1B1,
    const float* __restrict__ M1W2, const float* __restrict__ M1B2,
    const float* __restrict__ M1W3, const float* __restrict__ M1B3,
    float* __restrict__ l1_points,
    int* __restrict__ idx2, float r2b,
    const float* __restrict__ M2W1, const float* __restrict__ M2B1,
    const float* __restrict__ M2W2, const float* __restrict__ M2B2,
    const float* __restrict__ M2W3, const float* __restrict__ M2B3,
    float* __restrict__ out1)
{
    const int l = blockIdx.x;
    const int t = threadIdx.x;
    const int lane = t & 63;
    const int wid  = t >> 6;

    __shared__ unsigned long long wb[4];
    __shared__ float cw[4];
    __shared__ __align__(16) float ldsA[32*132];   // 16896 B (multi-purpose)
    __shared__ __align__(16) float ldsB[32*128];   // 16384 B
    __shared__ int sidx_sh[64];

    if (l < L_B1) {
        // ---------------- fps1 (R6-exact body) ----------------
        const int m = l & 15;
        const int b = l >> 4;
        const float* xb = xyz + (size_t)b * 6 * N1;
        const int base = m * (N1 / FPS1_M);
        float px[8], py[8], pz[8], dd[8];
#pragma unroll
        for (int j = 0; j < 8; ++j) {
            int n = base + t + j * 256;
            px[j] = xb[n];
            py[j] = xb[N1 + n];
            pz[j] = xb[2*N1 + n];
            dd[j] = 1e10f;
        }
        float cx = xb[0], cy = xb[N1], cz = xb[2*N1];

        for (int s = 0; s < NP1; ++s) {
            if (m == 0 && t == 0) {
                float* o = new_xyz1 + ((size_t)b*NP1 + s)*3;
                astore_f(o+0, cx); astore_f(o+1, cy); astore_f(o+2, cz);
            }
            if (s == NP1 - 1) break;

            float bv = -1.0f; int bi = base + t;
#pragma unroll
            for (int j = 0; j < 8; ++j) {
                float d  = dist3(px[j],py[j],pz[j],cx,cy,cz);
                float nd = fminf(dd[j], d);
                dd[j] = nd;
                if (nd > bv) { bv = nd; bi = base + t + j*256; }
            }
            unsigned long long pk = ((unsigned long long)__float_as_uint(bv) << 15)
                                  | (unsigned long long)(32767 - bi);
            pk = shflmax64(pk, 1);  pk = shflmax64(pk, 2);  pk = shflmax64(pk, 4);
            pk = shflmax64(pk, 8);  pk = shflmax64(pk, 16); pk = shflmax64(pk, 32);
            if (lane == 0) wb[wid] = pk;
            __syncthreads();

            if (wid == 0) {
                unsigned long long k4 = (lane < 4) ? wb[lane] : 0ull;
                k4 = shflmax64(k4, 1); k4 = shflmax64(k4, 2);
                unsigned long long* slotPar = bests + ((size_t)b*2 + (s & 1))*FPS1_M;
                if (lane == 0)
                    __hip_atomic_store(slotPar + m, (k4 << 10) | (unsigned long long)s,
                                       __ATOMIC_RELAXED, __HIP_MEMORY_SCOPE_AGENT);
                unsigned long long myv = 0; bool done = (lane >= FPS1_M);
                float ccx = 0.f, ccy = 0.f, ccz = 0.f;
                while (__ballot(done) != 0xFFFFFFFFFFFFFFFFull) {
                    if (!done) {
                        unsigned long long v = __hip_atomic_load(slotPar + lane,
                                                 __ATOMIC_RELAXED, __HIP_MEMORY_SCOPE_AGENT);
                        if ((unsigned)(v & 1023ull) == (unsigned)s) {
                            done = true; myv = v;
                            int idx = 32767 - (int)((v >> 10) & 0x7fffull);
                            ccx = xb[idx]; ccy = xb[N1 + idx]; ccz = xb[2*N1 + idx];
                        }
                    }
                }
                unsigned long long w = myv;
                w = shflmax64(w, 1); w = shflmax64(w, 2); w = shflmax64(w, 4); w = shflmax64(w, 8);
                int wl = (int)__ffsll(__ballot(myv == w)) - 1;
                float ncx = __shfl(ccx, wl, 64);
                float ncy = __shfl(ccy, wl, 64);
                float ncz = __shfl(ccz, wl, 64);
                if (lane == 0) { cw[0] = ncx; cw[1] = ncy; cw[2] = ncz; }
            }
            __syncthreads();
            cx = cw[0]; cy = cw[1]; cz = cw[2];
        }
        return;
    }

    if (l < L_F2) {
        // ---------------- ball1: s-major, 1 wave/centroid ----------------
        const int i = l - L_B1;
        const int b = i & 7;                 // batch inner
        const int s = (i >> 3)*4 + wid;      // s outer -> earliest s dispatched first
        const float* xb = xyz + (size_t)b*6*N1;
        const float* cp = new_xyz1 + ((size_t)b*NP1 + s)*3;
        float cx = poll_f<32>(cp+0), cy = poll_f<32>(cp+1), cz = poll_f<32>(cp+2);

        float snew = sumsq3(cx,cy,cz);
        int* out = idx1 + ((size_t)b*NP1 + s)*NS1;
        int cnt = 0, first = 0;
        for (int ch = 0; ch < N1/64; ++ch) {
            int n = ch*64 + lane;
            float x = xb[n], y = xb[N1+n], z = xb[2*N1+n];
            float sx  = sumsq3(x,y,z);
            float dt  = dot3(cx,cy,cz,x,y,z);
            float sqr = fsub(fadd(snew, sx), fmul(2.0f, dt));
            bool inb = !(sqr > r2a);
            unsigned long long mask = __ballot(inb);
            if (mask) {
                if (cnt == 0) first = ch*64 + (int)(__ffsll((unsigned long long)mask) - 1);
                if (inb) {
                    int pos = cnt + (int)__popcll(mask & ((1ull << lane) - 1ull));
                    if (pos < NS1) astore_i(out + pos, n);
                }
                cnt += (int)__popcll(mask);
                if (cnt >= NS1) break;
            }
        }
        int c = cnt < NS1 ? cnt : NS1;
        if (lane < NS1 && lane >= c) astore_i(out + lane, first);
        return;
    }

    if (l < L_M1) {
        // ---------------- fps2: poll-stage new_xyz1, 1-wave FPS ----------------
        const int b = l - L_F2;
        float* c3 = ldsA;
        const float* src = new_xyz1 + (size_t)b*N2*3;
        for (int e = t; e < N2*3; e += 256) c3[e] = poll_f<2>(src + e);
        __syncthreads();
        if (t >= 64) return;

        float px[8], py[8], pz[8], dd[8];
#pragma unroll
        for (int j = 0; j < 8; ++j) {
            int n = t + j*64;
            px[j] = c3[n*3]; py[j] = c3[n*3+1]; pz[j] = c3[n*3+2];
            dd[j] = 1e10f;
        }
        int cur = 0;
        for (int s = 0; s < NP2; ++s) {
            float cx = c3[cur*3], cy = c3[cur*3+1], cz = c3[cur*3+2];
            if (t == 0) {
                float* o = new_xyz2 + ((size_t)b*NP2 + s)*3;
                astore_f(o+0, cx); astore_f(o+1, cy); astore_f(o+2, cz);
                out0[b*3*NP2 + s]         = cx;
                out0[b*3*NP2 + NP2 + s]   = cy;
                out0[b*3*NP2 + 2*NP2 + s] = cz;
            }
            float bv = -1.0f; int bi = 0;
#pragma unroll
            for (int j = 0; j < 8; ++j) {
                float d  = dist3(px[j],py[j],pz[j],cx,cy,cz);
                float nd = fminf(dd[j], d);
                dd[j] = nd;
                int n = t + j*64;
                if (nd > bv) { bv = nd; bi = n; }
            }
            unsigned long long pk = ((unsigned long long)__float_as_uint(bv) << 9)
                                  | (unsigned long long)(511 - bi);
            pk = shflmax64(pk, 1);  pk = shflmax64(pk, 2);  pk = shflmax64(pk, 4);
            pk = shflmax64(pk, 8);  pk = shflmax64(pk, 16); pk = shflmax64(pk, 32);
            cur = 511 - (int)(pk & 511ull);
        }
        return;
    }

    if (l < L_B2) {
        // ---------------- mlp1: s-major, 1 centroid/block ----------------
        const int i = l - L_M1;
        const int b = i & 7;                 // batch inner
        const int s = i >> 3;                // s outer
        const float* xb = xyz + (size_t)b*6*N1;
        float (*inb6)[6]   = (float(*)[6])ldsA;
        float (*h1m)[64]   = (float(*)[64])(ldsA + 192);
        float (*h2m)[64]   = (float(*)[64])ldsB;
        float (*redm)[128] = (float(*)[128])(ldsB + 2048);

        const float* cp = new_xyz1 + ((size_t)b*NP1 + s)*3;
        float c0 = poll_f<32>(cp+0), c1 = poll_f<32>(cp+1), c2 = poll_f<32>(cp+2);
        if (t < NS1) sidx_sh[t] = poll_i<32>(idx1 + ((size_t)b*NP1+s)*NS1 + t);
        __syncthreads();
        if (t < NS1*6) {
            int k = t / 6, c = t % 6;
            int n = sidx_sh[k];
            float v = xb[(size_t)c*N1 + n];
            if (c == 0) v -= c0; else if (c == 1) v -= c1; else if (c == 2) v -= c2;
            inb6[k][c] = v;
        }
        __syncthreads();
        {   // L1
            int o = t & 63, kg = t >> 6;
            float w[6];
#pragma unroll
            for (int c = 0; c < 6; ++c) w[c] = M1W1[o*6+c];
            float bias = M1B1[o];
#pragma unroll
            for (int kk = 0; kk < 8; ++kk) {
                int k = kg*8 + kk;
                float a = 0.f;
#pragma unroll
                for (int c = 0; c < 6; ++c) a = fmaf(inb6[k][c], w[c], a);
                h1m[k][o] = fmaxf(a + bias, 0.f);
            }
        }
        __syncthreads();
        {   // L2: 64 -> 64
            int o = t & 63, kg = t >> 6;
            float acc[8] = {};
            for (int ch = 0; ch < 8; ++ch) {
                const float4 wa = *(const float4*)&M1W2[o*64 + ch*8];
                const float4 wbv = *(const float4*)&M1W2[o*64 + ch*8 + 4];
#pragma unroll
                for (int kk = 0; kk < 8; ++kk) {
                    int k = kg*8+kk;
                    const float4 a0 = *(const float4*)&h1m[k][ch*8];
                    const float4 a1 = *(const float4*)&h1m[k][ch*8+4];
                    acc[kk] = fmaf(a0.x, wa.x, acc[kk]);
                    acc[kk] = fmaf(a0.y, wa.y, acc[kk]);
                    acc[kk] = fmaf(a0.z, wa.z, acc[kk]);
                    acc[kk] = fmaf(a0.w, wa.w, acc[kk]);
                    acc[kk] = fmaf(a1.x, wbv.x, acc[kk]);
                    acc[kk] = fmaf(a1.y, wbv.y, acc[kk]);
                    acc[kk] = fmaf(a1.z, wbv.z, acc[kk]);
                    acc[kk] = fmaf(a1.w, wbv.w, acc[kk]);
                }
            }
            float bias = M1B2[o];
#pragma unroll
            for (int kk = 0; kk < 8; ++kk) h2m[kg*8+kk][o] = fmaxf(acc[kk] + bias, 0.f);
        }
        __syncthreads();
        {   // L3: 64 -> 128 + max over samples
            int o = t & 127, kg = t >> 7;
            float acc[16] = {};
            for (int ch = 0; ch < 8; ++ch) {
                const float4 wa = *(const float4*)&M1W3[o*64 + ch*8];
                const float4 wbv = *(const float4*)&M1W3[o*64 + ch*8 + 4];
#pragma unroll
                for (int kk = 0; kk < 16; ++kk) {
                    int k = kg*16+kk;
                    const float4 a0 = *(const float4*)&h2m[k][ch*8];
                    const float4 a1 = *(const float4*)&h2m[k][ch*8+4];
                    acc[kk] = fmaf(a0.x, wa.x, acc[kk]);
                    acc[kk] = fmaf(a0.y, wa.y, acc[kk]);
                    acc[kk] = fmaf(a0.z, wa.z, acc[kk]);
                    acc[kk] = fmaf(a0.w, wa.w, acc[kk]);
                    acc[kk] = fmaf(a1.x, wbv.x, acc[kk]);
                    acc[kk] = fmaf(a1.y, wbv.y, acc[kk]);
                    acc[kk] = fmaf(a1.z, wbv.z, acc[kk]);
                    acc[kk] = fmaf(a1.w, wbv.w, acc[kk]);
                }
            }
            float bias = M1B3[o];
            float m = -1e30f;
#pragma unroll
            for (int kk = 0; kk < 16; ++kk) m = fmaxf(m, fmaxf(acc[kk] + bias, 0.f));
            redm[kg][o] = m;
        }
        __syncthreads();
        if (t < 128) {
            float m = fmaxf(redm[0][t], redm[1][t]);
            astore_f(l1_points + ((size_t)b*NP1+s)*128 + t, m);
        }
        return;
    }

    if (l < L_M2) {
        // ---------------- ball2: s-major, 1 wave/centroid ----------------
        const int i = l - L_B2;
        const int b = i & 7;                 // batch inner
        const int s = (i >> 3)*4 + wid;      // s outer
        const float* pb = new_xyz1 + (size_t)b*N2*3;
        const float* cp = new_xyz2 + ((size_t)b*NP2 + s)*3;
        float cx = poll_f<32>(cp+0), cy = poll_f<32>(cp+1), cz = poll_f<32>(cp+2);
        float snew = sumsq3(cx,cy,cz);
        int* out = idx2 + ((size_t)b*NP2 + s)*NS2;
        int cnt = 0, first = 0;
        for (int ch = 0; ch < N2/64; ++ch) {
            int n = ch*64 + lane;
            float x = poll_f<8>(&pb[n*3]), y = poll_f<8>(&pb[n*3+1]), z = poll_f<8>(&pb[n*3+2]);
            float sx  = sumsq3(x,y,z);
            float dt  = dot3(cx,cy,cz,x,y,z);
            float sqr = fsub(fadd(snew, sx), fmul(2.0f, dt));
            bool inb = !(sqr > r2b);
            unsigned long long mask = __ballot(inb);
            if (mask) {
                if (cnt == 0) first = ch*64 + (int)(__ffsll((unsigned long long)mask) - 1);
                if (inb) {
                    int pos = cnt + (int)__popcll(mask & ((1ull << lane) - 1ull));
                    if (pos < NS2) astore_i(out + pos, n);
                }
                cnt += (int)__popcll(mask);
                if (cnt >= NS2) break;
            }
        }
        int c = cnt < NS2 ? cnt : NS2;
        if (lane >= c) astore_i(out + lane, first);
        return;
    }

    // ---------------- mlp2: s-major, 1 centroid/block (R6 body + polls, LDS-aliased) ----------------
    {
        const int i = l - L_M2;
        const int b = i & 7;                 // batch inner
        const int s = i >> 3;                // s outer
        float (*inb2)[132] = (float(*)[132])ldsA;   // aliased with h2_
        float (*h1_)[128]  = (float(*)[128])ldsB;
        float (*h2_)[128]  = (float(*)[128])ldsA;

        const float* cp = new_xyz2 + ((size_t)b*NP2+s)*3;
        float c0 = poll_f<32>(cp+0), c1 = poll_f<32>(cp+1), c2 = poll_f<32>(cp+2);
        if (t < NS2) sidx_sh[t] = poll_i<32>(idx2 + ((size_t)b*NP2+s)*NS2 + t);

        const int o1 = t & 63, o2 = o1 + 64, g = t >> 6;
        float vmax0 = -1e30f, vmax1 = -1e30f;

        for (int half = 0; half < 2; ++half) {
            __syncthreads();
            for (int e = t; e < 32*128; e += 256) {
                int kk = e >> 7, c = e & 127;
                int n = sidx_sh[half*32 + kk];
                inb2[kk][c] = poll_f<8>(l1_points + ((size_t)b*N2 + n)*128 + c);
            }
            for (int e = t; e < 32*3; e += 256) {
                int kk = e / 3, c = e % 3;
                int n = sidx_sh[half*32 + kk];
                inb2[kk][128 + c] = poll_f<8>(new_xyz1 + ((size_t)b*N2 + n)*3 + c)
                                  - (c==0 ? c0 : (c==1 ? c1 : c2));
            }
            __syncthreads();
            {   // L1: 131 -> 128, 2 outputs x 8 samples per thread
                float accA[8] = {}, accB[8] = {};
                for (int ch = 0; ch < 16; ++ch) {
                    float wa[8], wbv[8];
#pragma unroll
                    for (int j = 0; j < 8; ++j) {
                        wa[j]  = M2W1[o1*131 + 3 + ch*8 + j];
                        wbv[j] = M2W1[o2*131 + 3 + ch*8 + j];
                    }
#pragma unroll
                    for (int kk = 0; kk < 8; ++kk) {
                        int k = g*8 + kk;
                        const float4 a0 = *(const float4*)&inb2[k][ch*8];
                        const float4 a1 = *(const float4*)&inb2[k][ch*8+4];
                        accA[kk] = fmaf(a0.x, wa[0], accA[kk]);
                        accA[kk] = fmaf(a0.y, wa[1], accA[kk]);
                        accA[kk] = fmaf(a0.z, wa[2], accA[kk]);
                        accA[kk] = fmaf(a0.w, wa[3], accA[kk]);
                        accA[kk] = fmaf(a1.x, wa[4], accA[kk]);
                        accA[kk] = fmaf(a1.y, wa[5], accA[kk]);
                        accA[kk] = fmaf(a1.z, wa[6], accA[kk]);
                        accA[kk] = fmaf(a1.w, wa[7], accA[kk]);
                        accB[kk] = fmaf(a0.x, wbv[0], accB[kk]);
                        accB[kk] = fmaf(a0.y, wbv[1], accB[kk]);
                        accB[kk] = fmaf(a0.z, wbv[2], accB[kk]);
                        accB[kk] = fmaf(a0.w, wbv[3], accB[kk]);
                        accB[kk] = fmaf(a1.x, wbv[4], accB[kk]);
                        accB[kk] = fmaf(a1.y, wbv[5], accB[kk]);
                        accB[kk] = fmaf(a1.z, wbv[6], accB[kk]);
                        accB[kk] = fmaf(a1.w, wbv[7], accB[kk]);
                    }
                }
                float ta0=M2W1[o1*131+0], ta1=M2W1[o1*131+1], ta2=M2W1[o1*131+2];
                float tb0=M2W1[o2*131+0], tb1=M2W1[o2*131+1], tb2=M2W1[o2*131+2];
                float biasA = M2B1[o1], biasB = M2B1[o2];
#pragma unroll
                for (int kk = 0; kk < 8; ++kk) {
                    int k = g*8 + kk;
                    float f0 = inb2[k][128], f1 = inb2[k][129], f2 = inb2[k][130];
                    float vA = accA[kk];
                    vA = fmaf(f0, ta0, vA); vA = fmaf(f1, ta1, vA); vA = fmaf(f2, ta2, vA);
                    float vB = accB[kk];
                    vB = fmaf(f0, tb0, vB); vB = fmaf(f1, tb1, vB); vB = fmaf(f2, tb2, vB);
                    h1_[k][o1] = fmaxf(vA + biasA, 0.f);
                    h1_[k][o2] = fmaxf(vB + biasB, 0.f);
                }
            }
            __syncthreads();
            {   // L2: 128 -> 128 (writes h2_ = alias of inb2; inb2 dead now)
                float accA[8] = {}, accB[8] = {};
                for (int ch = 0; ch < 16; ++ch) {
                    const float4 wa0 = *(const float4*)&M2W2[o1*128 + ch*8];
                    const float4 wa1 = *(const float4*)&M2W2[o1*128 + ch*8 + 4];
                    const float4 wb0 = *(const float4*)&M2W2[o2*128 + ch*8];
                    const float4 wb1 = *(const float4*)&M2W2[o2*128 + ch*8 + 4];
#pragma unroll
                    for (int kk = 0; kk < 8; ++kk) {
                        int k = g*8 + kk;
                        const float4 a0 = *(const float4*)&h1_[k][ch*8];
                        const float4 a1 = *(const float4*)&h1_[k][ch*8+4];
                        accA[kk] = fmaf(a0.x, wa0.x, accA[kk]);
                        accA[kk] = fmaf(a0.y, wa0.y, accA[kk]);
                        accA[kk] = fmaf(a0.z, wa0.z, accA[kk]);
                        accA[kk] = fmaf(a0.w, wa0.w, accA[kk]);
                        accA[kk] = fmaf(a1.x, wa1.x, accA[kk]);
                        accA[kk] = fmaf(a1.y, wa1.y, accA[kk]);
                        accA[kk] = fmaf(a1.z, wa1.z, accA[kk]);
                        accA[kk] = fmaf(a1.w, wa1.w, accA[kk]);
                        accB[kk] = fmaf(a0.x, wb0.x, accB[kk]);
                        accB[kk] = fmaf(a0.y, wb0.y, accB[kk]);
                        accB[kk] = fmaf(a0.z, wb0.z, accB[kk]);
                        accB[kk] = fmaf(a0.w, wb0.w, accB[kk]);
                        accB[kk] = fmaf(a1.x, wb1.x, accB[kk]);
                        accB[kk] = fmaf(a1.y, wb1.y, accB[kk]);
                        accB[kk] = fmaf(a1.z, wb1.z, accB[kk]);
                        accB[kk] = fmaf(a1.w, wb1.w, accB[kk]);
                    }
                }
                float biasA = M2B2[o1], biasB = M2B2[o2];
#pragma unroll
                for (int kk = 0; kk < 8; ++kk) {
                    int k = g*8 + kk;
                    h2_[k][o1] = fmaxf(accA[kk] + biasA, 0.f);
                    h2_[k][o2] = fmaxf(accB[kk] + biasB, 0.f);
                }
            }
            __syncthreads();
            {   // L3: 128 -> 285, fold max over this half's 32 samples
                {
                    float acc[32] = {};
                    for (int ch = 0; ch < 16; ++ch) {
                        const float4 w0 = *(const float4*)&M2W3[t*128 + ch*8];
                        const float4 w1 = *(const float4*)&M2W3[t*128 + ch*8 + 4];
#pragma unroll
                        for (int kk = 0; kk < 32; ++kk) {
                            const float4 a0 = *(const float4*)&h2_[kk][ch*8];
                            const float4 a1 = *(const float4*)&h2_[kk][ch*8+4];
                            acc[kk] = fmaf(a0.x, w0.x, acc[kk]);
                            acc[kk] = fmaf(a0.y, w0.y, acc[kk]);
                            acc[kk] = fmaf(a0.z, w0.z, acc[kk]);
                            acc[kk] = fmaf(a0.w, w0.w, acc[kk]);
                            acc[kk] = fmaf(a1.x, w1.x, acc[kk]);
                            acc[kk] = fmaf(a1.y, w1.y, acc[kk]);
                            acc[kk] = fmaf(a1.z, w1.z, acc[kk]);
                            acc[kk] = fmaf(a1.w, w1.w, acc[kk]);
                        }
                    }
                    float bias = M2B3[t];
                    float mm = vmax0;
#pragma unroll
                    for (int kk = 0; kk < 32; ++kk) mm = fmaxf(mm, fmaxf(acc[kk] + bias, 0.f));
                    vmax0 = mm;
                }
                if (t < 29) {
                    int o = t + 256;
                    float acc[32] = {};
                    for (int ch = 0; ch < 16; ++ch) {
                        const float4 w0 = *(const float4*)&M2W3[o*128 + ch*8];
                        const float4 w1 = *(const float4*)&M2W3[o*128 + ch*8 + 4];
#pragma unroll
                        for (int kk = 0; kk < 32; ++kk) {
                            const float4 a0 = *(const float4*)&h2_[kk][ch*8];
                            const float4 a1 = *(const float4*)&h2_[kk][ch*8+4];
                            acc[kk] = fmaf(a0.x, w0.x, acc[kk]);
                            acc[kk] = fmaf(a0.y, w0.y, acc[kk]);
                            acc[kk] = fmaf(a0.z, w0.z, acc[kk]);
                            acc[kk] = fmaf(a0.w, w0.w, acc[kk]);
                            acc[kk] = fmaf(a1.x, w1.x, acc[kk]);
                            acc[kk] = fmaf(a1.y, w1.y, acc[kk]);
                            acc[kk] = fmaf(a1.z, w1.z, acc[kk]);
                            acc[kk] = fmaf(a1.w, w1.w, acc[kk]);
                        }
                    }
                    float bias = M2B3[o];
                    float mm = vmax1;
#pragma unroll
                    for (int kk = 0; kk < 32; ++kk) mm = fmaxf(mm, fmaxf(acc[kk] + bias, 0.f));
                    vmax1 = mm;
                }
            }
        }
        out1[((size_t)b*NP2+s)*285 + t] = vmax0;
        if (t < 29) out1[((size_t)b*NP2+s)*285 + t + 256] = vmax1;
    }
}

extern "C" void kernel_launch(void* const* d_in, const int* in_sizes, int n_in,
                              void* d_out, int out_size, void* d_ws, size_t ws_size,
                              hipStream_t stream)
{
    (void)in_sizes; (void)n_in; (void)out_size; (void)ws_size;
    const float* xyz  = (const float*)d_in[0];
    const float* s1w1 = (const float*)d_in[1];  const float* s1b1 = (const float*)d_in[2];
    const float* s1w2 = (const float*)d_in[3];  const float* s1b2 = (const float*)d_in[4];
    const float* s1w3 = (const float*)d_in[5];  const float* s1b3 = (const float*)d_in[6];
    const float* s2w1 = (const float*)d_in[7];  const float* s2b1 = (const float*)d_in[8];
    const float* s2w2 = (const float*)d_in[9];  const float* s2b2 = (const float*)d_in[10];
    const float* s2w3 = (const float*)d_in[11]; const float* s2b3 = (const float*)d_in[12];

    float* ws        = (float*)d_ws;
    float* new_xyz1  = ws;                  // 8*512*3   = 12288 f
    float* new_xyz2  = ws + 12288;          // 8*256*3   = 6144 f
    float* l1_points = ws + 18432;          // 8*512*128 = 524288 f
    int*   idx1      = (int*)(ws + 542720); // 8*512*32  = 131072 i
    int*   idx2      = idx1 + 131072;       // 8*256*64  = 131072 i
    unsigned long long* bests = (unsigned long long*)(ws + 804864); // 256 u64

    float* out0 = (float*)d_out;            // (8,3,256)
    float* out1 = out0 + 8*3*256;           // (8,256,285)

    const float r2a = (float)(0.025*0.025);
    const float r2b = (float)(0.05*0.05);

    mega_kernel<<<dim3(L_TOT), dim3(256), 0, stream>>>(xyz,
        new_xyz1, bests, idx1, r2a, new_xyz2, out0,
        s1w1,s1b1,s1w2,s1b2,s1w3,s1b3, l1_points,
        idx2, r2b,
        s2w1,s2b1,s2w2,s2b2,s2w3,s2b3, out1);
}

// Round 16
// 1572.566 us; speedup vs baseline: 1.5991x; 1.0769x over previous
//
#include <hip/hip_runtime.h>

#define N1 32768
#define NP1 512
#define NS1 32
#define N2 512
#define NP2 256
#define NS2 64
#define POISON 0xAAAAAAAAu

// ---- exact-rounding helpers: replicate reference op-by-op (NO fma/contract) ----
__device__ __forceinline__ float fadd(float a, float b){ return __fadd_rn(a,b); }
__device__ __forceinline__ float fmul(float a, float b){ return __fmul_rn(a,b); }
__device__ __forceinline__ float fsub(float a, float b){ return __fsub_rn(a,b); }

__device__ __forceinline__ float dist3(float px,float py,float pz,float cx,float cy,float cz){
    float dx = fsub(px,cx), dy = fsub(py,cy), dz = fsub(pz,cz);
    return fadd(fadd(fmul(dx,dx), fmul(dy,dy)), fmul(dz,dz));
}
__device__ __forceinline__ float sumsq3(float x,float y,float z){
    return fadd(fadd(fmul(x,x), fmul(y,y)), fmul(z,z));
}
__device__ __forceinline__ float dot3(float ax,float ay,float az,float bx,float by,float bz){
    return fadd(fadd(fmul(ax,bx), fmul(ay,by)), fmul(az,bz));
}
__device__ __forceinline__ unsigned long long shflmax64(unsigned long long k, int off){
    unsigned long long o = __shfl_xor(k, off, 64);
    return o > k ? o : k;
}

// ---- agent-scope atomic publish / poison-poll consume ----
__device__ __forceinline__ void astore_f(float* p, float v){
    __hip_atomic_store((unsigned*)p, __float_as_uint(v), __ATOMIC_RELAXED, __HIP_MEMORY_SCOPE_AGENT);
}
__device__ __forceinline__ void astore_i(int* p, int v){
    __hip_atomic_store((unsigned*)p, (unsigned)v, __ATOMIC_RELAXED, __HIP_MEMORY_SCOPE_AGENT);
}
template<int SLP>
__device__ __forceinline__ float poll_f(const float* p){
    unsigned v;
    for(;;){
        v = __hip_atomic_load((const unsigned*)p, __ATOMIC_RELAXED, __HIP_MEMORY_SCOPE_AGENT);
        if (v != POISON) break;
        __builtin_amdgcn_s_sleep(SLP);
    }
    return __uint_as_float(v);
}
template<int SLP>
__device__ __forceinline__ int poll_i(const int* p){
    unsigned v;
    for(;;){
        v = __hip_atomic_load((const unsigned*)p, __ATOMIC_RELAXED, __HIP_MEMORY_SCOPE_AGENT);
        if (v != POISON) break;
        __builtin_amdgcn_s_sleep(SLP);
    }
    return (int)v;
}

// ==================  MEGA KERNEL (R15) + fps1 XCD-affinity swizzle  ==================
// Single change vs R15: fps1 block mapping is now b = l&7, m = l>>3, so all
// 16 blocks of batch b sit at linear positions ≡ b (mod 8) -> same XCD under
// round-robin dispatch -> the batch's exchange cache-lines and centroid reads
// stay in that XCD's L2 (~200 cyc RT) instead of crossing dies (~600-900).
// Heuristic only: if the mapping differs, performance is unchanged and
// correctness is unaffected (placement never affects the protocol).
//   [0,128)      fps1   b=l&7, m=l>>3  (XCD affinity)
//   [128,1152)   ball1  s-major: b=i&7, s=(i>>3)*4+wid
//   [1152,1160)  fps2   1 blk/batch
//   [1160,5256)  mlp1   s-major: b=i&7, s=i>>3
//   [5256,5768)  ball2  s-major: b=i&7, s=(i>>3)*4+wid
//   [5768,7816)  mlp2   s-major: b=i&7, s=i>>3
#define FPS1_M  16
#define L_B1   128
#define L_F2   1152
#define L_M1   1160
#define L_B2   5256
#define L_M2   5768
#define L_TOT  7816

__global__ __launch_bounds__(256) void mega_kernel(const float* __restrict__ xyz,
    float* __restrict__ new_xyz1, unsigned long long* __restrict__ bests,
    int* __restrict__ idx1, float r2a,
    float* __restrict__ new_xyz2, float* __restrict__ out0,
    const float* __restrict__ M1W1, const float* __restrict__ M1B1,
    const float* __restrict__ M1W2, const float* __restrict__ M1B2,
    const float* __restrict__ M1W3, const float* __restrict__ M1B3,
    float* __restrict__ l1_points,
    int* __restrict__ idx2, float r2b,
    const float* __restrict__ M2W1, const float* __restrict__ M2B1,
    const float* __restrict__ M2W2, const float* __restrict__ M2B2,
    const float* __restrict__ M2W3, const float* __restrict__ M2B3,
    float* __restrict__ out1)
{
    const int l = blockIdx.x;
    const int t = threadIdx.x;
    const int lane = t & 63;
    const int wid  = t >> 6;

    __shared__ unsigned long long wb[4];
    __shared__ float cw[4];
    __shared__ __align__(16) float ldsA[32*132];   // 16896 B (multi-purpose)
    __shared__ __align__(16) float ldsB[32*128];   // 16384 B
    __shared__ int sidx_sh[64];

    if (l < L_B1) {
        // ---------------- fps1 (R6-exact body; XCD-affinity mapping) ----------------
        const int b = l & 7;               // batch  <-> XCD (round-robin heuristic)
        const int m = l >> 3;              // chunk within batch
        const float* xb = xyz + (size_t)b * 6 * N1;
        const int base = m * (N1 / FPS1_M);
        float px[8], py[8], pz[8], dd[8];
#pragma unroll
        for (int j = 0; j < 8; ++j) {
            int n = base + t + j * 256;
            px[j] = xb[n];
            py[j] = xb[N1 + n];
            pz[j] = xb[2*N1 + n];
            dd[j] = 1e10f;
        }
        float cx = xb[0], cy = xb[N1], cz = xb[2*N1];

        for (int s = 0; s < NP1; ++s) {
            if (m == 0 && t == 0) {
                float* o = new_xyz1 + ((size_t)b*NP1 + s)*3;
                astore_f(o+0, cx); astore_f(o+1, cy); astore_f(o+2, cz);
            }
            if (s == NP1 - 1) break;

            float bv = -1.0f; int bi = base + t;
#pragma unroll
            for (int j = 0; j < 8; ++j) {
                float d  = dist3(px[j],py[j],pz[j],cx,cy,cz);
                float nd = fminf(dd[j], d);
                dd[j] = nd;
                if (nd > bv) { bv = nd; bi = base + t + j*256; }
            }
            unsigned long long pk = ((unsigned long long)__float_as_uint(bv) << 15)
                                  | (unsigned long long)(32767 - bi);
            pk = shflmax64(pk, 1);  pk = shflmax64(pk, 2);  pk = shflmax64(pk, 4);
            pk = shflmax64(pk, 8);  pk = shflmax64(pk, 16); pk = shflmax64(pk, 32);
            if (lane == 0) wb[wid] = pk;
            __syncthreads();

            if (wid == 0) {
                unsigned long long k4 = (lane < 4) ? wb[lane] : 0ull;
                k4 = shflmax64(k4, 1); k4 = shflmax64(k4, 2);
                unsigned long long* slotPar = bests + ((size_t)b*2 + (s & 1))*FPS1_M;
                if (lane == 0)
                    __hip_atomic_store(slotPar + m, (k4 << 10) | (unsigned long long)s,
                                       __ATOMIC_RELAXED, __HIP_MEMORY_SCOPE_AGENT);
                unsigned long long myv = 0; bool done = (lane >= FPS1_M);
                float ccx = 0.f, ccy = 0.f, ccz = 0.f;
                while (__ballot(done) != 0xFFFFFFFFFFFFFFFFull) {
                    if (!done) {
                        unsigned long long v = __hip_atomic_load(slotPar + lane,
                                                 __ATOMIC_RELAXED, __HIP_MEMORY_SCOPE_AGENT);
                        if ((unsigned)(v & 1023ull) == (unsigned)s) {
                            done = true; myv = v;
                            int idx = 32767 - (int)((v >> 10) & 0x7fffull);
                            ccx = xb[idx]; ccy = xb[N1 + idx]; ccz = xb[2*N1 + idx];
                        }
                    }
                }
                unsigned long long w = myv;
                w = shflmax64(w, 1); w = shflmax64(w, 2); w = shflmax64(w, 4); w = shflmax64(w, 8);
                int wl = (int)__ffsll(__ballot(myv == w)) - 1;
                float ncx = __shfl(ccx, wl, 64);
                float ncy = __shfl(ccy, wl, 64);
                float ncz = __shfl(ccz, wl, 64);
                if (lane == 0) { cw[0] = ncx; cw[1] = ncy; cw[2] = ncz; }
            }
            __syncthreads();
            cx = cw[0]; cy = cw[1]; cz = cw[2];
        }
        return;
    }

    if (l < L_F2) {
        // ---------------- ball1: s-major, 1 wave/centroid ----------------
        const int i = l - L_B1;
        const int b = i & 7;                 // batch inner
        const int s = (i >> 3)*4 + wid;      // s outer -> earliest s dispatched first
        const float* xb = xyz + (size_t)b*6*N1;
        const float* cp = new_xyz1 + ((size_t)b*NP1 + s)*3;
        float cx = poll_f<32>(cp+0), cy = poll_f<32>(cp+1), cz = poll_f<32>(cp+2);

        float snew = sumsq3(cx,cy,cz);
        int* out = idx1 + ((size_t)b*NP1 + s)*NS1;
        int cnt = 0, first = 0;
        for (int ch = 0; ch < N1/64; ++ch) {
            int n = ch*64 + lane;
            float x = xb[n], y = xb[N1+n], z = xb[2*N1+n];
            float sx  = sumsq3(x,y,z);
            float dt  = dot3(cx,cy,cz,x,y,z);
            float sqr = fsub(fadd(snew, sx), fmul(2.0f, dt));
            bool inb = !(sqr > r2a);
            unsigned long long mask = __ballot(inb);
            if (mask) {
                if (cnt == 0) first = ch*64 + (int)(__ffsll((unsigned long long)mask) - 1);
                if (inb) {
                    int pos = cnt + (int)__popcll(mask & ((1ull << lane) - 1ull));
                    if (pos < NS1) astore_i(out + pos, n);
                }
                cnt += (int)__popcll(mask);
                if (cnt >= NS1) break;
            }
        }
        int c = cnt < NS1 ? cnt : NS1;
        if (lane < NS1 && lane >= c) astore_i(out + lane, first);
        return;
    }

    if (l < L_M1) {
        // ---------------- fps2: poll-stage new_xyz1, 1-wave FPS ----------------
        const int b = l - L_F2;
        float* c3 = ldsA;
        const float* src = new_xyz1 + (size_t)b*N2*3;
        for (int e = t; e < N2*3; e += 256) c3[e] = poll_f<2>(src + e);
        __syncthreads();
        if (t >= 64) return;

        float px[8], py[8], pz[8], dd[8];
#pragma unroll
        for (int j = 0; j < 8; ++j) {
            int n = t + j*64;
            px[j] = c3[n*3]; py[j] = c3[n*3+1]; pz[j] = c3[n*3+2];
            dd[j] = 1e10f;
        }
        int cur = 0;
        for (int s = 0; s < NP2; ++s) {
            float cx = c3[cur*3], cy = c3[cur*3+1], cz = c3[cur*3+2];
            if (t == 0) {
                float* o = new_xyz2 + ((size_t)b*NP2 + s)*3;
                astore_f(o+0, cx); astore_f(o+1, cy); astore_f(o+2, cz);
                out0[b*3*NP2 + s]         = cx;
                out0[b*3*NP2 + NP2 + s]   = cy;
                out0[b*3*NP2 + 2*NP2 + s] = cz;
            }
            float bv = -1.0f; int bi = 0;
#pragma unroll
            for (int j = 0; j < 8; ++j) {
                float d  = dist3(px[j],py[j],pz[j],cx,cy,cz);
                float nd = fminf(dd[j], d);
                dd[j] = nd;
                int n = t + j*64;
                if (nd > bv) { bv = nd; bi = n; }
            }
            unsigned long long pk = ((unsigned long long)__float_as_uint(bv) << 9)
                                  | (unsigned long long)(511 - bi);
            pk = shflmax64(pk, 1);  pk = shflmax64(pk, 2);  pk = shflmax64(pk, 4);
            pk = shflmax64(pk, 8);  pk = shflmax64(pk, 16); pk = shflmax64(pk, 32);
            cur = 511 - (int)(pk & 511ull);
        }
        return;
    }

    if (l < L_B2) {
        // ---------------- mlp1: s-major, 1 centroid/block ----------------
        const int i = l - L_M1;
        const int b = i & 7;                 // batch inner
        const int s = i >> 3;                // s outer
        const float* xb = xyz + (size_t)b*6*N1;
        float (*inb6)[6]   = (float(*)[6])ldsA;
        float (*h1m)[64]   = (float(*)[64])(ldsA + 192);
        float (*h2m)[64]   = (float(*)[64])ldsB;
        float (*redm)[128] = (float(*)[128])(ldsB + 2048);

        const float* cp = new_xyz1 + ((size_t)b*NP1 + s)*3;
        float c0 = poll_f<32>(cp+0), c1 = poll_f<32>(cp+1), c2 = poll_f<32>(cp+2);
        if (t < NS1) sidx_sh[t] = poll_i<32>(idx1 + ((size_t)b*NP1+s)*NS1 + t);
        __syncthreads();
        if (t < NS1*6) {
            int k = t / 6, c = t % 6;
            int n = sidx_sh[k];
            float v = xb[(size_t)c*N1 + n];
            if (c == 0) v -= c0; else if (c == 1) v -= c1; else if (c == 2) v -= c2;
            inb6[k][c] = v;
        }
        __syncthreads();
        {   // L1
            int o = t & 63, kg = t >> 6;
            float w[6];
#pragma unroll
            for (int c = 0; c < 6; ++c) w[c] = M1W1[o*6+c];
            float bias = M1B1[o];
#pragma unroll
            for (int kk = 0; kk < 8; ++kk) {
                int k = kg*8 + kk;
                float a = 0.f;
#pragma unroll
                for (int c = 0; c < 6; ++c) a = fmaf(inb6[k][c], w[c], a);
                h1m[k][o] = fmaxf(a + bias, 0.f);
            }
        }
        __syncthreads();
        {   // L2: 64 -> 64
            int o = t & 63, kg = t >> 6;
            float acc[8] = {};
            for (int ch = 0; ch < 8; ++ch) {
                const float4 wa = *(const float4*)&M1W2[o*64 + ch*8];
                const float4 wbv = *(const float4*)&M1W2[o*64 + ch*8 + 4];
#pragma unroll
                for (int kk = 0; kk < 8; ++kk) {
                    int k = kg*8+kk;
                    const float4 a0 = *(const float4*)&h1m[k][ch*8];
                    const float4 a1 = *(const float4*)&h1m[k][ch*8+4];
                    acc[kk] = fmaf(a0.x, wa.x, acc[kk]);
                    acc[kk] = fmaf(a0.y, wa.y, acc[kk]);
                    acc[kk] = fmaf(a0.z, wa.z, acc[kk]);
                    acc[kk] = fmaf(a0.w, wa.w, acc[kk]);
                    acc[kk] = fmaf(a1.x, wbv.x, acc[kk]);
                    acc[kk] = fmaf(a1.y, wbv.y, acc[kk]);
                    acc[kk] = fmaf(a1.z, wbv.z, acc[kk]);
                    acc[kk] = fmaf(a1.w, wbv.w, acc[kk]);
                }
            }
            float bias = M1B2[o];
#pragma unroll
            for (int kk = 0; kk < 8; ++kk) h2m[kg*8+kk][o] = fmaxf(acc[kk] + bias, 0.f);
        }
        __syncthreads();
        {   // L3: 64 -> 128 + max over samples
            int o = t & 127, kg = t >> 7;
            float acc[16] = {};
            for (int ch = 0; ch < 8; ++ch) {
                const float4 wa = *(const float4*)&M1W3[o*64 + ch*8];
                const float4 wbv = *(const float4*)&M1W3[o*64 + ch*8 + 4];
#pragma unroll
                for (int kk = 0; kk < 16; ++kk) {
                    int k = kg*16+kk;
                    const float4 a0 = *(const float4*)&h2m[k][ch*8];
                    const float4 a1 = *(const float4*)&h2m[k][ch*8+4];
                    acc[kk] = fmaf(a0.x, wa.x, acc[kk]);
                    acc[kk] = fmaf(a0.y, wa.y, acc[kk]);
                    acc[kk] = fmaf(a0.z, wa.z, acc[kk]);
                    acc[kk] = fmaf(a0.w, wa.w, acc[kk]);
                    acc[kk] = fmaf(a1.x, wbv.x, acc[kk]);
                    acc[kk] = fmaf(a1.y, wbv.y, acc[kk]);
                    acc[kk] = fmaf(a1.z, wbv.z, acc[kk]);
                    acc[kk] = fmaf(a1.w, wbv.w, acc[kk]);
                }
            }
            float bias = M1B3[o];
            float m = -1e30f;
#pragma unroll
            for (int kk = 0; kk < 16; ++kk) m = fmaxf(m, fmaxf(acc[kk] + bias, 0.f));
            redm[kg][o] = m;
        }
        __syncthreads();
        if (t < 128) {
            float m = fmaxf(redm[0][t], redm[1][t]);
            astore_f(l1_points + ((size_t)b*NP1+s)*128 + t, m);
        }
        return;
    }

    if (l < L_M2) {
        // ---------------- ball2: s-major, 1 wave/centroid ----------------
        const int i = l - L_B2;
        const int b = i & 7;                 // batch inner
        const int s = (i >> 3)*4 + wid;      // s outer
        const float* pb = new_xyz1 + (size_t)b*N2*3;
        const float* cp = new_xyz2 + ((size_t)b*NP2 + s)*3;
        float cx = poll_f<32>(cp+0), cy = poll_f<32>(cp+1), cz = poll_f<32>(cp+2);
        float snew = sumsq3(cx,cy,cz);
        int* out = idx2 + ((size_t)b*NP2 + s)*NS2;
        int cnt = 0, first = 0;
        for (int ch = 0; ch < N2/64; ++ch) {
            int n = ch*64 + lane;
            float x = poll_f<8>(&pb[n*3]), y = poll_f<8>(&pb[n*3+1]), z = poll_f<8>(&pb[n*3+2]);
            float sx  = sumsq3(x,y,z);
            float dt  = dot3(cx,cy,cz,x,y,z);
            float sqr = fsub(fadd(snew, sx), fmul(2.0f, dt));
            bool inb = !(sqr > r2b);
            unsigned long long mask = __ballot(inb);
            if (mask) {
                if (cnt == 0) first = ch*64 + (int)(__ffsll((unsigned long long)mask) - 1);
                if (inb) {
                    int pos = cnt + (int)__popcll(mask & ((1ull << lane) - 1ull));
                    if (pos < NS2) astore_i(out + pos, n);
                }
                cnt += (int)__popcll(mask);
                if (cnt >= NS2) break;
            }
        }
        int c = cnt < NS2 ? cnt : NS2;
        if (lane >= c) astore_i(out + lane, first);
        return;
    }

    // ---------------- mlp2: s-major, 1 centroid/block (R6 body + polls, LDS-aliased) ----------------
    {
        const int i = l - L_M2;
        const int b = i & 7;                 // batch inner
        const int s = i >> 3;                // s outer
        float (*inb2)[132] = (float(*)[132])ldsA;   // aliased with h2_
        float (*h1_)[128]  = (float(*)[128])ldsB;
        float (*h2_)[128]  = (float(*)[128])ldsA;

        const float* cp = new_xyz2 + ((size_t)b*NP2+s)*3;
        float c0 = poll_f<32>(cp+0), c1 = poll_f<32>(cp+1), c2 = poll_f<32>(cp+2);
        if (t < NS2) sidx_sh[t] = poll_i<32>(idx2 + ((size_t)b*NP2+s)*NS2 + t);

        const int o1 = t & 63, o2 = o1 + 64, g = t >> 6;
        float vmax0 = -1e30f, vmax1 = -1e30f;

        for (int half = 0; half < 2; ++half) {
            __syncthreads();
            for (int e = t; e < 32*128; e += 256) {
                int kk = e >> 7, c = e & 127;
                int n = sidx_sh[half*32 + kk];
                inb2[kk][c] = poll_f<8>(l1_points + ((size_t)b*N2 + n)*128 + c);
            }
            for (int e = t; e < 32*3; e += 256) {
                int kk = e / 3, c = e % 3;
                int n = sidx_sh[half*32 + kk];
                inb2[kk][128 + c] = poll_f<8>(new_xyz1 + ((size_t)b*N2 + n)*3 + c)
                                  - (c==0 ? c0 : (c==1 ? c1 : c2));
            }
            __syncthreads();
            {   // L1: 131 -> 128, 2 outputs x 8 samples per thread
                float accA[8] = {}, accB[8] = {};
                for (int ch = 0; ch < 16; ++ch) {
                    float wa[8], wbv[8];
#pragma unroll
                    for (int j = 0; j < 8; ++j) {
                        wa[j]  = M2W1[o1*131 + 3 + ch*8 + j];
                        wbv[j] = M2W1[o2*131 + 3 + ch*8 + j];
                    }
#pragma unroll
                    for (int kk = 0; kk < 8; ++kk) {
                        int k = g*8 + kk;
                        const float4 a0 = *(const float4*)&inb2[k][ch*8];
                        const float4 a1 = *(const float4*)&inb2[k][ch*8+4];
                        accA[kk] = fmaf(a0.x, wa[0], accA[kk]);
                        accA[kk] = fmaf(a0.y, wa[1], accA[kk]);
                        accA[kk] = fmaf(a0.z, wa[2], accA[kk]);
                        accA[kk] = fmaf(a0.w, wa[3], accA[kk]);
                        accA[kk] = fmaf(a1.x, wa[4], accA[kk]);
                        accA[kk] = fmaf(a1.y, wa[5], accA[kk]);
                        accA[kk] = fmaf(a1.z, wa[6], accA[kk]);
                        accA[kk] = fmaf(a1.w, wa[7], accA[kk]);
                        accB[kk] = fmaf(a0.x, wbv[0], accB[kk]);
                        accB[kk] = fmaf(a0.y, wbv[1], accB[kk]);
                        accB[kk] = fmaf(a0.z, wbv[2], accB[kk]);
                        accB[kk] = fmaf(a0.w, wbv[3], accB[kk]);
                        accB[kk] = fmaf(a1.x, wbv[4], accB[kk]);
                        accB[kk] = fmaf(a1.y, wbv[5], accB[kk]);
                        accB[kk] = fmaf(a1.z, wbv[6], accB[kk]);
                        accB[kk] = fmaf(a1.w, wbv[7], accB[kk]);
                    }
                }
                float ta0=M2W1[o1*131+0], ta1=M2W1[o1*131+1], ta2=M2W1[o1*131+2];
                float tb0=M2W1[o2*131+0], tb1=M2W1[o2*131+1], tb2=M2W1[o2*131+2];
                float biasA = M2B1[o1], biasB = M2B1[o2];
#pragma unroll
                for (int kk = 0; kk < 8; ++kk) {
                    int k = g*8 + kk;
                    float f0 = inb2[k][128], f1 = inb2[k][129], f2 = inb2[k][130];
                    float vA = accA[kk];
                    vA = fmaf(f0, ta0, vA); vA = fmaf(f1, ta1, vA); vA = fmaf(f2, ta2, vA);
                    float vB = accB[kk];
                    vB = fmaf(f0, tb0, vB); vB = fmaf(f1, tb1, vB); vB = fmaf(f2, tb2, vB);
                    h1_[k][o1] = fmaxf(vA + biasA, 0.f);
                    h1_[k][o2] = fmaxf(vB + biasB, 0.f);
                }
            }
            __syncthreads();
            {   // L2: 128 -> 128 (writes h2_ = alias of inb2; inb2 dead now)
                float accA[8] = {}, accB[8] = {};
                for (int ch = 0; ch < 16; ++ch) {
                    const float4 wa0 = *(const float4*)&M2W2[o1*128 + ch*8];
                    const float4 wa1 = *(const float4*)&M2W2[o1*128 + ch*8 + 4];
                    const float4 wb0 = *(const float4*)&M2W2[o2*128 + ch*8];
                    const float4 wb1 = *(const float4*)&M2W2[o2*128 + ch*8 + 4];
#pragma unroll
                    for (int kk = 0; kk < 8; ++kk) {
                        int k = g*8 + kk;
                        const float4 a0 = *(const float4*)&h1_[k][ch*8];
                        const float4 a1 = *(const float4*)&h1_[k][ch*8+4];
                        accA[kk] = fmaf(a0.x, wa0.x, accA[kk]);
                        accA[kk] = fmaf(a0.y, wa0.y, accA[kk]);
                        accA[kk] = fmaf(a0.z, wa0.z, accA[kk]);
                        accA[kk] = fmaf(a0.w, wa0.w, accA[kk]);
                        accA[kk] = fmaf(a1.x, wa1.x, accA[kk]);
                        accA[kk] = fmaf(a1.y, wa1.y, accA[kk]);
                        accA[kk] = fmaf(a1.z, wa1.z, accA[kk]);
                        accA[kk] = fmaf(a1.w, wa1.w, accA[kk]);
                        accB[kk] = fmaf(a0.x, wb0.x, accB[kk]);
                        accB[kk] = fmaf(a0.y, wb0.y, accB[kk]);
                        accB[kk] = fmaf(a0.z, wb0.z, accB[kk]);
                        accB[kk] = fmaf(a0.w, wb0.w, accB[kk]);
                        accB[kk] = fmaf(a1.x, wb1.x, accB[kk]);
                        accB[kk] = fmaf(a1.y, wb1.y, accB[kk]);
                        accB[kk] = fmaf(a1.z, wb1.z, accB[kk]);
                        accB[kk] = fmaf(a1.w, wb1.w, accB[kk]);
                    }
                }
                float biasA = M2B2[o1], biasB = M2B2[o2];
#pragma unroll
                for (int kk = 0; kk < 8; ++kk) {
                    int k = g*8 + kk;
                    h2_[k][o1] = fmaxf(accA[kk] + biasA, 0.f);
                    h2_[k][o2] = fmaxf(accB[kk] + biasB, 0.f);
                }
            }
            __syncthreads();
            {   // L3: 128 -> 285, fold max over this half's 32 samples
                {
                    float acc[32] = {};
                    for (int ch = 0; ch < 16; ++ch) {
                        const float4 w0 = *(const float4*)&M2W3[t*128 + ch*8];
                        const float4 w1 = *(const float4*)&M2W3[t*128 + ch*8 + 4];
#pragma unroll
                        for (int kk = 0; kk < 32; ++kk) {
                            const float4 a0 = *(const float4*)&h2_[kk][ch*8];
                            const float4 a1 = *(const float4*)&h2_[kk][ch*8+4];
                            acc[kk] = fmaf(a0.x, w0.x, acc[kk]);
                            acc[kk] = fmaf(a0.y, w0.y, acc[kk]);
                            acc[kk] = fmaf(a0.z, w0.z, acc[kk]);
                            acc[kk] = fmaf(a0.w, w0.w, acc[kk]);
                            acc[kk] = fmaf(a1.x, w1.x, acc[kk]);
                            acc[kk] = fmaf(a1.y, w1.y, acc[kk]);
                            acc[kk] = fmaf(a1.z, w1.z, acc[kk]);
                            acc[kk] = fmaf(a1.w, w1.w, acc[kk]);
                        }
                    }
                    float bias = M2B3[t];
                    float mm = vmax0;
#pragma unroll
                    for (int kk = 0; kk < 32; ++kk) mm = fmaxf(mm, fmaxf(acc[kk] + bias, 0.f));
                    vmax0 = mm;
                }
                if (t < 29) {
                    int o = t + 256;
                    float acc[32] = {};
                    for (int ch = 0; ch < 16; ++ch) {
                        const float4 w0 = *(const float4*)&M2W3[o*128 + ch*8];
                        const float4 w1 = *(const float4*)&M2W3[o*128 + ch*8 + 4];
#pragma unroll
                        for (int kk = 0; kk < 32; ++kk) {
                            const float4 a0 = *(const float4*)&h2_[kk][ch*8];
                            const float4 a1 = *(const float4*)&h2_[kk][ch*8+4];
                            acc[kk] = fmaf(a0.x, w0.x, acc[kk]);
                            acc[kk] = fmaf(a0.y, w0.y, acc[kk]);
                            acc[kk] = fmaf(a0.z, w0.z, acc[kk]);
                            acc[kk] = fmaf(a0.w, w0.w, acc[kk]);
                            acc[kk] = fmaf(a1.x, w1.x, acc[kk]);
                            acc[kk] = fmaf(a1.y, w1.y, acc[kk]);
                            acc[kk] = fmaf(a1.z, w1.z, acc[kk]);
                            acc[kk] = fmaf(a1.w, w1.w, acc[kk]);
                        }
                    }
                    float bias = M2B3[o];
                    float mm = vmax1;
#pragma unroll
                    for (int kk = 0; kk < 32; ++kk) mm = fmaxf(mm, fmaxf(acc[kk] + bias, 0.f));
                    vmax1 = mm;
                }
            }
        }
        out1[((size_t)b*NP2+s)*285 + t] = vmax0;
        if (t < 29) out1[((size_t)b*NP2+s)*285 + t + 256] = vmax1;
    }
}

extern "C" void kernel_launch(void* const* d_in, const int* in_sizes, int n_in,
                              void* d_out, int out_size, void* d_ws, size_t ws_size,
                              hipStream_t stream)
{
    (void)in_sizes; (void)n_in; (void)out_size; (void)ws_size;
    const float* xyz  = (const float*)d_in[0];
    const float* s1w1 = (const float*)d_in[1];  const float* s1b1 = (const float*)d_in[2];
    const float* s1w2 = (const float*)d_in[3];  const float* s1b2 = (const float*)d_in[4];
    const float* s1w3 = (const float*)d_in[5];  const float* s1b3 = (const float*)d_in[6];
    const float* s2w1 = (const float*)d_in[7];  const float* s2b1 = (const float*)d_in[8];
    const float* s2w2 = (const float*)d_in[9];  const float* s2b2 = (const float*)d_in[10];
    const float* s2w3 = (const float*)d_in[11]; const float* s2b3 = (const float*)d_in[12];

    float* ws        = (float*)d_ws;
    float* new_xyz1  = ws;                  // 8*512*3   = 12288 f
    float* new_xyz2  = ws + 12288;          // 8*256*3   = 6144 f
    float* l1_points = ws + 18432;          // 8*512*128 = 524288 f
    int*   idx1      = (int*)(ws + 542720); // 8*512*32  = 131072 i
    int*   idx2      = idx1 + 131072;       // 8*256*64  = 131072 i
    unsigned long long* bests = (unsigned long long*)(ws + 804864); // 256 u64

    float* out0 = (float*)d_out;            // (8,3,256)
    float* out1 = out0 + 8*3*256;           // (8,256,285)

    const float r2a = (float)(0.025*0.025);
    const float r2b = (float)(0.05*0.05);

    mega_kernel<<<dim3(L_TOT), dim3(256), 0, stream>>>(xyz,
        new_xyz1, bests, idx1, r2a, new_xyz2, out0,
        s1w1,s1b1,s1w2,s1b2,s1w3,s1b3, l1_points,
        idx2, r2b,
        s2w1,s2b1,s2w2,s2b2,s2w3,s2b3, out1);
}